// Round 3
// baseline (176.009 us; speedup 1.0000x reference)
//
#include <hip/hip_runtime.h>

#define BATCH 8
#define S_LEN 2048
#define DDIM 512
#define UDIM 512
#define WIN_L 128
#define WIN_R 128
#define PP 296   // P LDS pitch (f16): 288 + 8 (37 granules/row, conflict-free)

typedef _Float16 f16;
typedef __attribute__((ext_vector_type(8))) _Float16 f16x8;
typedef __attribute__((ext_vector_type(4))) _Float16 f16x4;
typedef __attribute__((ext_vector_type(4))) float f32x4;

__device__ __forceinline__ void gload_lds16(const void* g, void* l) {
  __builtin_amdgcn_global_load_lds((const __attribute__((address_space(1))) void*)g,
                                   (__attribute__((address_space(3))) void*)l, 16, 0, 0);
}

// ---------------- prep: transpose W [D][U] fp32 -> WT [U][D] f16 ----------------
__global__ void prep(const float* __restrict__ Wq, const float* __restrict__ Wk,
                     const float* __restrict__ Wv, f16* __restrict__ WT) {
  __shared__ float t[32][33];
  int id = blockIdx.x;
  int zx = id & 15, zy = (id >> 4) & 15, zz = id >> 8;
  const float* W = zz == 0 ? Wq : (zz == 1 ? Wk : Wv);
  f16* WTz = WT + (size_t)zz * DDIM * UDIM;
  int tx = threadIdx.x & 31, ty = threadIdx.x >> 5;  // 32 x 8
  int n0 = zx * 32, k0 = zy * 32;
  for (int i = 0; i < 4; i++) {
    int r = ty * 4 + i;
    t[r][tx] = W[(size_t)(k0 + r) * UDIM + n0 + tx];
  }
  __syncthreads();
  for (int i = 0; i < 4; i++) {
    int r = ty * 4 + i;
    WTz[(size_t)(n0 + r) * DDIM + k0 + tx] = (f16)t[tx][r];
  }
}

// ---------------- QKV GEMM v6: counted-vmcnt pipeline, A single-buffer ----------------
// Per K-step: [vmcnt(8)+lgkm(0); bar] -> read A-frags -> [lgkm(0); bar] ->
//   cvt ap->Al (only ap outstanding: clean wait) -> issue B(t+1) gload_lds ->
//   issue ap(t+2) -> read B-frags (float to MFMA) -> setprio(1) MFMA x32 setprio(0).
// vmcnt never drains to 0 in the loop; B(t+1) has the bf+MFMA phase to land.
// LDS 48 KB (A 16 single + B 2x16) -> 3 blocks/CU.
__global__ __launch_bounds__(256, 3) void gemm_qkv(
    const float* __restrict__ X32, const f16* __restrict__ WT,
    const float* __restrict__ bq, const float* __restrict__ bk, const float* __restrict__ bv,
    f16* __restrict__ QKV, f16* __restrict__ VT) {
  int g = blockIdx.x;
  int xcd = g & 7, j = g >> 3;           // j in [0,192)
  int m_blk = xcd * 16 + (j & 15);       // 0..127
  int rest = j >> 4;                     // 0..11
  int ny = rest & 3, z = rest >> 2;      // ny 0..3, z 0..2

  const f16* WTz = WT + (size_t)z * DDIM * UDIM;   // [U][D] layout
  const float* bias = z == 0 ? bq : (z == 1 ? bk : bv);
  f16* out = QKV + (size_t)z * (BATCH * S_LEN) * UDIM;

  __shared__ f16 Al[2][128 * 32];        // [chunk]        16 KB (single K-buffer)
  __shared__ f16 Bl[2][2][128 * 32];     // [kbuf][chunk]  32 KB

  int tid = threadIdx.x, wv = tid >> 6, ln = tid & 63;
  int m0 = m_blk * 128, n0 = ny * 128;
  int wm = (wv >> 1) * 64, wn = (wv & 1) * 64;
  int lm = ln & 15, lq = ln >> 4;
  int srow = ln >> 2;                                  // staging row within 16-row slab
  int scol = ((ln & 3) ^ ((ln >> 3) & 3)) * 8;         // swizzled 16B-chunk (write/source side)
  int rsw  = (lq ^ ((lm >> 1) & 3)) * 8;               // swizzled 16B-chunk (read side)

  f32x4 acc[4][4];
#pragma unroll
  for (int mt = 0; mt < 4; mt++)
    for (int nt = 0; nt < 4; nt++)
      for (int r = 0; r < 4; r++) acc[mt][nt][r] = 0.f;

  const float* abase = X32 + (size_t)(m0 + wv * 32 + srow) * DDIM + (ln & 3) * 8;

  // ---- prologue: ap(0) regs, B(0)->Bl[0], cvt ap(0)->Al, ap(1) regs ----
  float4 ap[2][2][2];
#pragma unroll
  for (int cc = 0; cc < 2; cc++)
#pragma unroll
    for (int h = 0; h < 2; h++) {
      const float* p = abase + (size_t)(h * 16) * DDIM + cc * 32;
      ap[cc][h][0] = *(const float4*)p;
      ap[cc][h][1] = *(const float4*)(p + 4);
    }
#pragma unroll
  for (int half = 0; half < 2; half++) {
    int r0 = half * 64 + wv * 16;  // wave-uniform
#pragma unroll
    for (int cc = 0; cc < 2; cc++)
      gload_lds16(WTz + (size_t)(n0 + r0 + srow) * DDIM + cc * 32 + scol, &Bl[0][cc][r0 * 32]);
  }
  __builtin_amdgcn_sched_barrier(0);
#pragma unroll
  for (int cc = 0; cc < 2; cc++)
#pragma unroll
    for (int h = 0; h < 2; h++) {
      float4 p0 = ap[cc][h][0], p1 = ap[cc][h][1];
      f16x8 o;
      o[0] = (f16)p0.x; o[1] = (f16)p0.y; o[2] = (f16)p0.z; o[3] = (f16)p0.w;
      o[4] = (f16)p1.x; o[5] = (f16)p1.y; o[6] = (f16)p1.z; o[7] = (f16)p1.w;
      *(f16x8*)&Al[cc][(wv * 32 + h * 16 + srow) * 32 + scol] = o;
    }
#pragma unroll
  for (int cc = 0; cc < 2; cc++)
#pragma unroll
    for (int h = 0; h < 2; h++) {
      const float* p = abase + (size_t)(h * 16) * DDIM + 64 + cc * 32;
      ap[cc][h][0] = *(const float4*)p;
      ap[cc][h][1] = *(const float4*)(p + 4);
    }

  for (int t = 0; t < 8; ++t) {
    int cur = t & 1;
    // drain exactly the 4 B(t) gloads; 8 ap loads stay in flight across the barrier
    asm volatile("s_waitcnt vmcnt(8) lgkmcnt(0)" ::: "memory");
    __builtin_amdgcn_sched_barrier(0);
    __builtin_amdgcn_s_barrier();
    __builtin_amdgcn_sched_barrier(0);

    // ---- A fragments (must complete before Al overwrite below) ----
    f16x8 af[2][4];
#pragma unroll
    for (int cc = 0; cc < 2; cc++)
#pragma unroll
      for (int mt = 0; mt < 4; mt++)
        af[cc][mt] = *(const f16x8*)&Al[cc][(wm + mt * 16 + lm) * 32 + rsw];
    asm volatile("s_waitcnt lgkmcnt(0)" ::: "memory");
    __builtin_amdgcn_sched_barrier(0);
    __builtin_amdgcn_s_barrier();   // all waves done reading Al -> safe to overwrite
    __builtin_amdgcn_sched_barrier(0);

    // ---- cvt ap(t+1) -> Al; only ap outstanding here, so the wait is clean ----
#pragma unroll
    for (int cc = 0; cc < 2; cc++)
#pragma unroll
      for (int h = 0; h < 2; h++) {
        float4 p0 = ap[cc][h][0], p1 = ap[cc][h][1];
        f16x8 o;
        o[0] = (f16)p0.x; o[1] = (f16)p0.y; o[2] = (f16)p0.z; o[3] = (f16)p0.w;
        o[4] = (f16)p1.x; o[5] = (f16)p1.y; o[6] = (f16)p1.z; o[7] = (f16)p1.w;
        *(f16x8*)&Al[cc][(wv * 32 + h * 16 + srow) * 32 + scol] = o;
      }
    __builtin_amdgcn_sched_barrier(0);

    // ---- B(t+1) -> Bl[cur^1] (last iter re-loads k=448, keeps counts uniform) ----
    int kB = (t < 7 ? (t + 1) : 7) * 64;
#pragma unroll
    for (int half = 0; half < 2; half++) {
      int r0 = half * 64 + wv * 16;
#pragma unroll
      for (int cc = 0; cc < 2; cc++)
        gload_lds16(WTz + (size_t)(n0 + r0 + srow) * DDIM + kB + cc * 32 + scol,
                    &Bl[cur ^ 1][cc][r0 * 32]);
    }
    __builtin_amdgcn_sched_barrier(0);

    // ---- ap(t+2) global prefetch (clamped on tail) ----
    int kA = (t < 6 ? (t + 2) : 7) * 64;
#pragma unroll
    for (int cc = 0; cc < 2; cc++)
#pragma unroll
      for (int h = 0; h < 2; h++) {
        const float* p = abase + (size_t)(h * 16) * DDIM + kA + cc * 32;
        ap[cc][h][0] = *(const float4*)p;
        ap[cc][h][1] = *(const float4*)(p + 4);
      }

    // ---- B fragments (double-buffered: free to schedule into the MFMAs) + MFMA ----
    f16x8 bf[2][4];
#pragma unroll
    for (int cc = 0; cc < 2; cc++)
#pragma unroll
      for (int nt = 0; nt < 4; nt++)
        bf[cc][nt] = *(const f16x8*)&Bl[cur][cc][(wn + nt * 16 + lm) * 32 + rsw];

    __builtin_amdgcn_s_setprio(1);
#pragma unroll
    for (int cc = 0; cc < 2; cc++)
#pragma unroll
      for (int mt = 0; mt < 4; mt++)
#pragma unroll
        for (int nt = 0; nt < 4; nt++)
          acc[mt][nt] = __builtin_amdgcn_mfma_f32_16x16x32_f16(af[cc][mt], bf[cc][nt], acc[mt][nt], 0, 0, 0);
    __builtin_amdgcn_s_setprio(0);
  }
  // drain stragglers so pending gload_lds can't land in a reallocated LDS block
  asm volatile("s_waitcnt vmcnt(0)" ::: "memory");

  if (z == 2) {
#pragma unroll
    for (int mt = 0; mt < 4; mt++)
#pragma unroll
      for (int nt = 0; nt < 4; nt++) {
        int col = n0 + wn + nt * 16 + lm;          // u
        float bv_ = bias[col];
        int row0 = m0 + wm + mt * 16 + lq * 4;     // global s index (r=0)
        int bb = row0 >> 11, ss = row0 & 2047;
        f16x4 o;
        for (int r = 0; r < 4; r++) o[r] = (f16)(acc[mt][nt][r] + bv_);
        *(f16x4*)&VT[((size_t)bb * UDIM + col) * S_LEN + ss] = o;
      }
  } else {
#pragma unroll
    for (int mt = 0; mt < 4; mt++)
#pragma unroll
      for (int nt = 0; nt < 4; nt++) {
        int col = n0 + wn + nt * 16 + lm;
        float bv_ = bias[col];
        for (int r = 0; r < 4; r++) {
          int row = m0 + wm + mt * 16 + lq * 4 + r;
          out[(size_t)row * UDIM + col] = (f16)(acc[mt][nt][r] + bv_);
        }
      }
  }
}

// ---------------- sliding-window attention v7b (unchanged from round 2) ----------------
__global__ __launch_bounds__(256, 2) void attn(
    const f16* __restrict__ Q, const f16* __restrict__ K, const f16* __restrict__ VT,
    float* __restrict__ out) {
  __shared__ __align__(16) char ubuf[32 * 1024];     // Kl (32 KB) / Vl (32 KB) union
  __shared__ f16 Pb[32 * PP];                        // 18.9 KB
  __shared__ float wmax[2][32], wsum[2][32];
  f16* Kl = (f16*)ubuf;
  f16* Vl = (f16*)ubuf;

  int tid = threadIdx.x, wv = tid >> 6, ln = tid & 63;
  int lm = ln & 15, lq = ln >> 4;
  int b = blockIdx.x, q0 = blockIdx.y * 32;
  int rh = wv >> 1, kh = wv & 1;        // wave quarter: q-rows rh*16.., keys kh*16..
  const size_t base = (size_t)b * S_LEN;
  const int strip0 = q0 - WIN_L;        // strip keys [strip0, strip0+288)
  const int t_lo = strip0 < 0 ? (-strip0) >> 5 : 0;                 // first live 32-key tile
  int t_hi = (S_LEN - strip0) >> 5; if (t_hi > 9) t_hi = 9;         // one past last live

  // ---- Q fragments (A-operand), invariant ----
  f16x8 qf[16];
  {
    const f16* qrow = Q + (base + q0 + rh * 16 + lm) * (size_t)DDIM + lq * 8;
#pragma unroll
    for (int kk = 0; kk < 16; kk++) qf[kk] = *(const f16x8*)(qrow + kk * 32);
  }

  // ---- S phase: staged key-steps ----
  f32x4 sacc[9];
#pragma unroll
  for (int s = 0; s < 9; s++)
    for (int r = 0; r < 4; r++) sacc[s][r] = 0.f;

  int krow = kh * 16 + lm;
  int ksw = krow & 7;  // = lm & 7

#pragma unroll
  for (int s = 0; s < 9; s++) {
    if (s >= t_lo && s < t_hi) {  // block-uniform liveness
      int j0 = strip0 + s * 32;
#pragma unroll
      for (int i = 0; i < 8; i++) {
        int row = wv * 8 + i;
        int key = j0 + row;
        int kc = key < 0 ? 0 : (key > S_LEN - 1 ? S_LEN - 1 : key);
        // pre-swizzled source chunk: LDS[row][c] <- global[row][c ^ (row&7)]
        gload_lds16(K + (base + kc) * (size_t)DDIM + (ln ^ i) * 8, &Kl[row * 512]);
      }
      __syncthreads();
      f32x4 s0, s1;
      for (int r = 0; r < 4; r++) { s0[r] = 0.f; s1[r] = 0.f; }
#pragma unroll
      for (int kk = 0; kk < 16; kk += 2) {
        f16x8 b0 = *(const f16x8*)&Kl[krow * 512 + ((kk * 4 + lq) ^ ksw) * 8];
        f16x8 b1 = *(const f16x8*)&Kl[krow * 512 + (((kk + 1) * 4 + lq) ^ ksw) * 8];
        s0 = __builtin_amdgcn_mfma_f32_16x16x32_f16(qf[kk], b0, s0, 0, 0, 0);
        s1 = __builtin_amdgcn_mfma_f32_16x16x32_f16(qf[kk + 1], b1, s1, 0, 0, 0);
      }
      for (int r = 0; r < 4; r++) sacc[s][r] = s0[r] + s1[r];
      __syncthreads();
    }
  }

  // ---- mask + row max ----
  const float scale = 0.044194173824159216f;  // 1/sqrt(512)
  float mx[4] = {-1e30f, -1e30f, -1e30f, -1e30f};
#pragma unroll
  for (int s = 0; s < 9; s++) {
    int kj = strip0 + s * 32 + kh * 16 + lm;
#pragma unroll
    for (int r = 0; r < 4; r++) {
      int qi = q0 + rh * 16 + lq * 4 + r;
      float v = sacc[s][r] * scale;
      bool ok = (kj >= 0) && (kj < S_LEN) && (kj >= qi - WIN_L) && (kj <= qi + WIN_R);
      v = ok ? v : -1e30f;
      sacc[s][r] = v;
      mx[r] = fmaxf(mx[r], v);
    }
  }
#pragma unroll
  for (int r = 0; r < 4; r++) {
    mx[r] = fmaxf(mx[r], __shfl_xor(mx[r], 1));
    mx[r] = fmaxf(mx[r], __shfl_xor(mx[r], 2));
    mx[r] = fmaxf(mx[r], __shfl_xor(mx[r], 4));
    mx[r] = fmaxf(mx[r], __shfl_xor(mx[r], 8));
  }
  if (lm == 0) {
#pragma unroll
    for (int r = 0; r < 4; r++) wmax[kh][rh * 16 + lq * 4 + r] = mx[r];
  }
  __syncthreads();

  // ---- exp + P park + row sums ----
  float mrow[4], sum[4] = {0.f, 0.f, 0.f, 0.f};
#pragma unroll
  for (int r = 0; r < 4; r++) {
    int row = rh * 16 + lq * 4 + r;
    mrow[r] = fmaxf(wmax[0][row], wmax[1][row]);
  }
#pragma unroll
  for (int s = 0; s < 9; s++) {
#pragma unroll
    for (int r = 0; r < 4; r++) {
      float p = __expf(sacc[s][r] - mrow[r]);
      sum[r] += p;
      Pb[(rh * 16 + lq * 4 + r) * PP + s * 32 + kh * 16 + lm] = (f16)p;
    }
  }
#pragma unroll
  for (int r = 0; r < 4; r++) {
    sum[r] += __shfl_xor(sum[r], 1);
    sum[r] += __shfl_xor(sum[r], 2);
    sum[r] += __shfl_xor(sum[r], 4);
    sum[r] += __shfl_xor(sum[r], 8);
  }
  if (lm == 0) {
#pragma unroll
    for (int r = 0; r < 4; r++) wsum[kh][rh * 16 + lq * 4 + r] = sum[r];
  }
  __syncthreads();  // Pb + sums visible; Kl dead -> Vl may reuse ubuf

  // ---- PV phase: software-pipelined V staging ----
  f32x4 oacc[2][8];
#pragma unroll
  for (int mt = 0; mt < 2; mt++)
    for (int nt = 0; nt < 8; nt++)
      for (int r = 0; r < 4; r++) oacc[mt][nt][r] = 0.f;

  int vu = (tid >> 2), vc4 = tid & 3;
  int vsw = (vc4 ^ ((vu >> 1) & 3)) * 8;             // swizzled V write chunk
  int vrd = (lq ^ ((lm >> 1) & 3)) * 8;              // swizzled V read chunk
  const f16* vsrc = VT + ((size_t)b * UDIM + vu) * S_LEN;
  f16x8 vreg[8];
  {
    int j0 = strip0 + t_lo * 32;
    int key = j0 + vc4 * 8;
    int kc = key < 0 ? 0 : (key > S_LEN - 8 ? S_LEN - 8 : key);
#pragma unroll
    for (int i = 0; i < 8; i++) vreg[i] = *(const f16x8*)(vsrc + (size_t)(i * 64) * S_LEN + kc);
  }

  for (int t = t_lo; t < t_hi; t++) {
#pragma unroll
    for (int i = 0; i < 8; i++) *(f16x8*)&Vl[(i * 64 + vu) * 32 + vsw] = vreg[i];
    __syncthreads();
    if (t + 1 < t_hi) {  // prefetch next slab into regs; overlaps MFMAs below
      int j0 = strip0 + (t + 1) * 32;
      int key = j0 + vc4 * 8;
      int kc = key < 0 ? 0 : (key > S_LEN - 8 ? S_LEN - 8 : key);
#pragma unroll
      for (int i = 0; i < 8; i++) vreg[i] = *(const f16x8*)(vsrc + (size_t)(i * 64) * S_LEN + kc);
    }
    f16x8 pf0 = *(const f16x8*)&Pb[lm * PP + t * 32 + lq * 8];
    f16x8 pf1 = *(const f16x8*)&Pb[(16 + lm) * PP + t * 32 + lq * 8];
#pragma unroll
    for (int nt = 0; nt < 8; nt++) {
      f16x8 vvf = *(const f16x8*)&Vl[(wv * 128 + nt * 16 + lm) * 32 + vrd];
      oacc[0][nt] = __builtin_amdgcn_mfma_f32_16x16x32_f16(pf0, vvf, oacc[0][nt], 0, 0, 0);
      oacc[1][nt] = __builtin_amdgcn_mfma_f32_16x16x32_f16(pf1, vvf, oacc[1][nt], 0, 0, 0);
    }
    __syncthreads();
  }

  // ---- epilogue: O /= l, fp32 store ----
  float linv[2][4];
#pragma unroll
  for (int mt = 0; mt < 2; mt++)
    for (int r = 0; r < 4; r++) {
      int row = mt * 16 + lq * 4 + r;
      linv[mt][r] = 1.0f / (wsum[0][row] + wsum[1][row]);
    }
#pragma unroll
  for (int mt = 0; mt < 2; mt++)
    for (int nt = 0; nt < 8; nt++)
      for (int r = 0; r < 4; r++) {
        int row = q0 + mt * 16 + lq * 4 + r;
        int col = wv * 128 + nt * 16 + lm;
        out[(base + row) * (size_t)UDIM + col] = oacc[mt][nt][r] * linv[mt][r];
      }
}

extern "C" void kernel_launch(void* const* d_in, const int* in_sizes, int n_in,
                              void* d_out, int out_size, void* d_ws, size_t ws_size,
                              hipStream_t stream) {
  const float* x  = (const float*)d_in[0];
  const float* Wq = (const float*)d_in[1];
  const float* Wk = (const float*)d_in[2];
  const float* Wv = (const float*)d_in[3];
  const float* bq = (const float*)d_in[4];
  const float* bk = (const float*)d_in[5];
  const float* bv = (const float*)d_in[6];
  float* out = (float*)d_out;

  char* ws = (char*)d_ws;
  const size_t WT_BYTES  = (size_t)3 * DDIM * UDIM * 2;            // 1.5 MB
  const size_t QKV_BYTES = (size_t)3 * BATCH * S_LEN * UDIM * 2;   // 50.3 MB
  f16* WT  = (f16*)ws;
  f16* QKV = (f16*)(ws + WT_BYTES);
  f16* VT  = (f16*)(ws + WT_BYTES + QKV_BYTES);

  prep<<<768, 256, 0, stream>>>(Wq, Wk, Wv, WT);
  gemm_qkv<<<1536, 256, 0, stream>>>(x, WT, bq, bk, bv, QKV, VT);
  // attn: blockIdx.x = batch so linear id % 8 == batch -> XCD-local K/V in L2
  attn<<<dim3(BATCH, S_LEN / 32), 256, 0, stream>>>(
      QKV, QKV + (size_t)BATCH * S_LEN * UDIM, VT, out);
}

// Round 4
// 152.173 us; speedup vs baseline: 1.1566x; 1.1566x over previous
//
#include <hip/hip_runtime.h>

#define BATCH 8
#define S_LEN 2048
#define DDIM 512
#define UDIM 512
#define WIN_L 128
#define WIN_R 128
#define PP 296   // P LDS pitch (f16): 288 + 8 (37 granules/row, conflict-free)

typedef _Float16 f16;
typedef __attribute__((ext_vector_type(8))) _Float16 f16x8;
typedef __attribute__((ext_vector_type(4))) _Float16 f16x4;
typedef __attribute__((ext_vector_type(4))) float f32x4;

__device__ __forceinline__ void gload_lds16(const void* g, void* l) {
  __builtin_amdgcn_global_load_lds((const __attribute__((address_space(1))) void*)g,
                                   (__attribute__((address_space(3))) void*)l, 16, 0, 0);
}

// ---------------- prep2: W [D][U] fp32 -> WT [U][D] f16  AND  X fp32 -> X16 f16 ----------------
// blocks [0,768): W transpose; blocks [768, 768+4096): X cast (2048 f16/block).
__global__ void prep(const float* __restrict__ Wq, const float* __restrict__ Wk,
                     const float* __restrict__ Wv, const float* __restrict__ X32,
                     f16* __restrict__ WT, f16* __restrict__ X16) {
  int id = blockIdx.x;
  if (id < 768) {
    __shared__ float t[32][33];
    int zx = id & 15, zy = (id >> 4) & 15, zz = id >> 8;
    const float* W = zz == 0 ? Wq : (zz == 1 ? Wk : Wv);
    f16* WTz = WT + (size_t)zz * DDIM * UDIM;
    int tx = threadIdx.x & 31, ty = threadIdx.x >> 5;  // 32 x 8
    int n0 = zx * 32, k0 = zy * 32;
    for (int i = 0; i < 4; i++) {
      int r = ty * 4 + i;
      t[r][tx] = W[(size_t)(k0 + r) * UDIM + n0 + tx];
    }
    __syncthreads();
    for (int i = 0; i < 4; i++) {
      int r = ty * 4 + i;
      WTz[(size_t)(n0 + r) * DDIM + k0 + tx] = (f16)t[tx][r];
    }
  } else {
    size_t i0 = ((size_t)(id - 768) * 256 + threadIdx.x) * 8;
    float4 a = *(const float4*)(X32 + i0);
    float4 b = *(const float4*)(X32 + i0 + 4);
    f16x8 o;
    o[0] = (f16)a.x; o[1] = (f16)a.y; o[2] = (f16)a.z; o[3] = (f16)a.w;
    o[4] = (f16)b.x; o[5] = (f16)b.y; o[6] = (f16)b.z; o[7] = (f16)b.w;
    *(f16x8*)(X16 + i0) = o;
  }
}

// ---------------- QKV GEMM v7: pure m97 structure ----------------
// Both operands staged f16 via global_load_lds (16B), single-buffered 32 KB LDS,
// plain __syncthreads (accept compiler's vmcnt(0) drain; TLP hides it: 5 blocks/CU),
// XOR-swizzled chunks (verified conflict-free in r1). No inline asm, no sched games.
__global__ __launch_bounds__(256, 3) void gemm_qkv(
    const f16* __restrict__ X16, const f16* __restrict__ WT,
    const float* __restrict__ bq, const float* __restrict__ bk, const float* __restrict__ bv,
    f16* __restrict__ QKV, f16* __restrict__ VT) {
  int g = blockIdx.x;
  int xcd = g & 7, j = g >> 3;           // j in [0,192)
  int m_blk = xcd * 16 + (j & 15);       // 0..127
  int rest = j >> 4;                     // 0..11
  int ny = rest & 3, z = rest >> 2;      // ny 0..3, z 0..2

  const f16* WTz = WT + (size_t)z * DDIM * UDIM;   // [U][D] layout
  const float* bias = z == 0 ? bq : (z == 1 ? bk : bv);
  f16* out = QKV + (size_t)z * (BATCH * S_LEN) * UDIM;

  __shared__ f16 Al[2][128 * 32];        // [chunk] 16 KB
  __shared__ f16 Bl[2][128 * 32];        // [chunk] 16 KB

  int tid = threadIdx.x, wv = tid >> 6, ln = tid & 63;
  int m0 = m_blk * 128, n0 = ny * 128;
  int wm = (wv >> 1) * 64, wn = (wv & 1) * 64;
  int lm = ln & 15, lq = ln >> 4;
  int srow = ln >> 2;                                  // staging row within 16-row slab
  int scol = ((ln & 3) ^ ((ln >> 3) & 3)) * 8;         // swizzled 16B-chunk (source side)
  int rsw  = (lq ^ ((lm >> 1) & 3)) * 8;               // swizzled 16B-chunk (read side)

  f32x4 acc[4][4];
#pragma unroll
  for (int mt = 0; mt < 4; mt++)
    for (int nt = 0; nt < 4; nt++)
      for (int r = 0; r < 4; r++) acc[mt][nt][r] = 0.f;

  for (int k0 = 0; k0 < DDIM; k0 += 64) {
    // ---- stage A and B, both async global->LDS (pre-swizzled source chunk) ----
#pragma unroll
    for (int half = 0; half < 2; half++) {
      int r0 = half * 64 + wv * 16;  // wave-uniform
#pragma unroll
      for (int cc = 0; cc < 2; cc++) {
        gload_lds16(X16 + (size_t)(m0 + r0 + srow) * DDIM + k0 + cc * 32 + scol, &Al[cc][r0 * 32]);
        gload_lds16(WTz + (size_t)(n0 + r0 + srow) * DDIM + k0 + cc * 32 + scol, &Bl[cc][r0 * 32]);
      }
    }
    __syncthreads();

#pragma unroll
    for (int cc = 0; cc < 2; cc++) {
      f16x8 af[4], bfr[4];
#pragma unroll
      for (int mt = 0; mt < 4; mt++) af[mt] = *(const f16x8*)&Al[cc][(wm + mt * 16 + lm) * 32 + rsw];
#pragma unroll
      for (int nt = 0; nt < 4; nt++) bfr[nt] = *(const f16x8*)&Bl[cc][(wn + nt * 16 + lm) * 32 + rsw];
#pragma unroll
      for (int mt = 0; mt < 4; mt++)
#pragma unroll
        for (int nt = 0; nt < 4; nt++)
          acc[mt][nt] = __builtin_amdgcn_mfma_f32_16x16x32_f16(af[mt], bfr[nt], acc[mt][nt], 0, 0, 0);
    }
    __syncthreads();
  }

  if (z == 2) {
#pragma unroll
    for (int mt = 0; mt < 4; mt++)
#pragma unroll
      for (int nt = 0; nt < 4; nt++) {
        int col = n0 + wn + nt * 16 + lm;          // u
        float bv_ = bias[col];
        int row0 = m0 + wm + mt * 16 + lq * 4;     // global s index (r=0)
        int bb = row0 >> 11, ss = row0 & 2047;
        f16x4 o;
        for (int r = 0; r < 4; r++) o[r] = (f16)(acc[mt][nt][r] + bv_);
        *(f16x4*)&VT[((size_t)bb * UDIM + col) * S_LEN + ss] = o;
      }
  } else {
#pragma unroll
    for (int mt = 0; mt < 4; mt++)
#pragma unroll
      for (int nt = 0; nt < 4; nt++) {
        int col = n0 + wn + nt * 16 + lm;
        float bv_ = bias[col];
        for (int r = 0; r < 4; r++) {
          int row = m0 + wm + mt * 16 + lq * 4 + r;
          out[(size_t)row * UDIM + col] = (f16)(acc[mt][nt][r] + bv_);
        }
      }
  }
}

// ---------------- sliding-window attention v7b (unchanged) ----------------
__global__ __launch_bounds__(256, 2) void attn(
    const f16* __restrict__ Q, const f16* __restrict__ K, const f16* __restrict__ VT,
    float* __restrict__ out) {
  __shared__ __align__(16) char ubuf[32 * 1024];     // Kl (32 KB) / Vl (32 KB) union
  __shared__ f16 Pb[32 * PP];                        // 18.9 KB
  __shared__ float wmax[2][32], wsum[2][32];
  f16* Kl = (f16*)ubuf;
  f16* Vl = (f16*)ubuf;

  int tid = threadIdx.x, wv = tid >> 6, ln = tid & 63;
  int lm = ln & 15, lq = ln >> 4;
  int b = blockIdx.x, q0 = blockIdx.y * 32;
  int rh = wv >> 1, kh = wv & 1;        // wave quarter: q-rows rh*16.., keys kh*16..
  const size_t base = (size_t)b * S_LEN;
  const int strip0 = q0 - WIN_L;        // strip keys [strip0, strip0+288)
  const int t_lo = strip0 < 0 ? (-strip0) >> 5 : 0;                 // first live 32-key tile
  int t_hi = (S_LEN - strip0) >> 5; if (t_hi > 9) t_hi = 9;         // one past last live

  // ---- Q fragments (A-operand), invariant ----
  f16x8 qf[16];
  {
    const f16* qrow = Q + (base + q0 + rh * 16 + lm) * (size_t)DDIM + lq * 8;
#pragma unroll
    for (int kk = 0; kk < 16; kk++) qf[kk] = *(const f16x8*)(qrow + kk * 32);
  }

  // ---- S phase: staged key-steps ----
  f32x4 sacc[9];
#pragma unroll
  for (int s = 0; s < 9; s++)
    for (int r = 0; r < 4; r++) sacc[s][r] = 0.f;

  int krow = kh * 16 + lm;
  int ksw = krow & 7;  // = lm & 7

#pragma unroll
  for (int s = 0; s < 9; s++) {
    if (s >= t_lo && s < t_hi) {  // block-uniform liveness
      int j0 = strip0 + s * 32;
#pragma unroll
      for (int i = 0; i < 8; i++) {
        int row = wv * 8 + i;
        int key = j0 + row;
        int kc = key < 0 ? 0 : (key > S_LEN - 1 ? S_LEN - 1 : key);
        // pre-swizzled source chunk: LDS[row][c] <- global[row][c ^ (row&7)]
        gload_lds16(K + (base + kc) * (size_t)DDIM + (ln ^ i) * 8, &Kl[row * 512]);
      }
      __syncthreads();
      f32x4 s0, s1;
      for (int r = 0; r < 4; r++) { s0[r] = 0.f; s1[r] = 0.f; }
#pragma unroll
      for (int kk = 0; kk < 16; kk += 2) {
        f16x8 b0 = *(const f16x8*)&Kl[krow * 512 + ((kk * 4 + lq) ^ ksw) * 8];
        f16x8 b1 = *(const f16x8*)&Kl[krow * 512 + (((kk + 1) * 4 + lq) ^ ksw) * 8];
        s0 = __builtin_amdgcn_mfma_f32_16x16x32_f16(qf[kk], b0, s0, 0, 0, 0);
        s1 = __builtin_amdgcn_mfma_f32_16x16x32_f16(qf[kk + 1], b1, s1, 0, 0, 0);
      }
      for (int r = 0; r < 4; r++) sacc[s][r] = s0[r] + s1[r];
      __syncthreads();
    }
  }

  // ---- mask + row max ----
  const float scale = 0.044194173824159216f;  // 1/sqrt(512)
  float mx[4] = {-1e30f, -1e30f, -1e30f, -1e30f};
#pragma unroll
  for (int s = 0; s < 9; s++) {
    int kj = strip0 + s * 32 + kh * 16 + lm;
#pragma unroll
    for (int r = 0; r < 4; r++) {
      int qi = q0 + rh * 16 + lq * 4 + r;
      float v = sacc[s][r] * scale;
      bool ok = (kj >= 0) && (kj < S_LEN) && (kj >= qi - WIN_L) && (kj <= qi + WIN_R);
      v = ok ? v : -1e30f;
      sacc[s][r] = v;
      mx[r] = fmaxf(mx[r], v);
    }
  }
#pragma unroll
  for (int r = 0; r < 4; r++) {
    mx[r] = fmaxf(mx[r], __shfl_xor(mx[r], 1));
    mx[r] = fmaxf(mx[r], __shfl_xor(mx[r], 2));
    mx[r] = fmaxf(mx[r], __shfl_xor(mx[r], 4));
    mx[r] = fmaxf(mx[r], __shfl_xor(mx[r], 8));
  }
  if (lm == 0) {
#pragma unroll
    for (int r = 0; r < 4; r++) wmax[kh][rh * 16 + lq * 4 + r] = mx[r];
  }
  __syncthreads();

  // ---- exp + P park + row sums ----
  float mrow[4], sum[4] = {0.f, 0.f, 0.f, 0.f};
#pragma unroll
  for (int r = 0; r < 4; r++) {
    int row = rh * 16 + lq * 4 + r;
    mrow[r] = fmaxf(wmax[0][row], wmax[1][row]);
  }
#pragma unroll
  for (int s = 0; s < 9; s++) {
#pragma unroll
    for (int r = 0; r < 4; r++) {
      float p = __expf(sacc[s][r] - mrow[r]);
      sum[r] += p;
      Pb[(rh * 16 + lq * 4 + r) * PP + s * 32 + kh * 16 + lm] = (f16)p;
    }
  }
#pragma unroll
  for (int r = 0; r < 4; r++) {
    sum[r] += __shfl_xor(sum[r], 1);
    sum[r] += __shfl_xor(sum[r], 2);
    sum[r] += __shfl_xor(sum[r], 4);
    sum[r] += __shfl_xor(sum[r], 8);
  }
  if (lm == 0) {
#pragma unroll
    for (int r = 0; r < 4; r++) wsum[kh][rh * 16 + lq * 4 + r] = sum[r];
  }
  __syncthreads();  // Pb + sums visible; Kl dead -> Vl may reuse ubuf

  // ---- PV phase: software-pipelined V staging ----
  f32x4 oacc[2][8];
#pragma unroll
  for (int mt = 0; mt < 2; mt++)
    for (int nt = 0; nt < 8; nt++)
      for (int r = 0; r < 4; r++) oacc[mt][nt][r] = 0.f;

  int vu = (tid >> 2), vc4 = tid & 3;
  int vsw = (vc4 ^ ((vu >> 1) & 3)) * 8;             // swizzled V write chunk
  int vrd = (lq ^ ((lm >> 1) & 3)) * 8;              // swizzled V read chunk
  const f16* vsrc = VT + ((size_t)b * UDIM + vu) * S_LEN;
  f16x8 vreg[8];
  {
    int j0 = strip0 + t_lo * 32;
    int key = j0 + vc4 * 8;
    int kc = key < 0 ? 0 : (key > S_LEN - 8 ? S_LEN - 8 : key);
#pragma unroll
    for (int i = 0; i < 8; i++) vreg[i] = *(const f16x8*)(vsrc + (size_t)(i * 64) * S_LEN + kc);
  }

  for (int t = t_lo; t < t_hi; t++) {
#pragma unroll
    for (int i = 0; i < 8; i++) *(f16x8*)&Vl[(i * 64 + vu) * 32 + vsw] = vreg[i];
    __syncthreads();
    if (t + 1 < t_hi) {  // prefetch next slab into regs; overlaps MFMAs below
      int j0 = strip0 + (t + 1) * 32;
      int key = j0 + vc4 * 8;
      int kc = key < 0 ? 0 : (key > S_LEN - 8 ? S_LEN - 8 : key);
#pragma unroll
      for (int i = 0; i < 8; i++) vreg[i] = *(const f16x8*)(vsrc + (size_t)(i * 64) * S_LEN + kc);
    }
    f16x8 pf0 = *(const f16x8*)&Pb[lm * PP + t * 32 + lq * 8];
    f16x8 pf1 = *(const f16x8*)&Pb[(16 + lm) * PP + t * 32 + lq * 8];
#pragma unroll
    for (int nt = 0; nt < 8; nt++) {
      f16x8 vvf = *(const f16x8*)&Vl[(wv * 128 + nt * 16 + lm) * 32 + vrd];
      oacc[0][nt] = __builtin_amdgcn_mfma_f32_16x16x32_f16(pf0, vvf, oacc[0][nt], 0, 0, 0);
      oacc[1][nt] = __builtin_amdgcn_mfma_f32_16x16x32_f16(pf1, vvf, oacc[1][nt], 0, 0, 0);
    }
    __syncthreads();
  }

  // ---- epilogue: O /= l, fp32 store ----
  float linv[2][4];
#pragma unroll
  for (int mt = 0; mt < 2; mt++)
    for (int r = 0; r < 4; r++) {
      int row = mt * 16 + lq * 4 + r;
      linv[mt][r] = 1.0f / (wsum[0][row] + wsum[1][row]);
    }
#pragma unroll
  for (int mt = 0; mt < 2; mt++)
    for (int nt = 0; nt < 8; nt++)
      for (int r = 0; r < 4; r++) {
        int row = q0 + mt * 16 + lq * 4 + r;
        int col = wv * 128 + nt * 16 + lm;
        out[(base + row) * (size_t)UDIM + col] = oacc[mt][nt][r] * linv[mt][r];
      }
}

extern "C" void kernel_launch(void* const* d_in, const int* in_sizes, int n_in,
                              void* d_out, int out_size, void* d_ws, size_t ws_size,
                              hipStream_t stream) {
  const float* x  = (const float*)d_in[0];
  const float* Wq = (const float*)d_in[1];
  const float* Wk = (const float*)d_in[2];
  const float* Wv = (const float*)d_in[3];
  const float* bq = (const float*)d_in[4];
  const float* bk = (const float*)d_in[5];
  const float* bv = (const float*)d_in[6];
  float* out = (float*)d_out;

  char* ws = (char*)d_ws;
  const size_t WT_BYTES  = (size_t)3 * DDIM * UDIM * 2;            // 1.5 MB
  const size_t QKV_BYTES = (size_t)3 * BATCH * S_LEN * UDIM * 2;   // 50.3 MB
  const size_t VT_BYTES  = (size_t)BATCH * S_LEN * UDIM * 2;       // 16.8 MB
  f16* WT  = (f16*)ws;
  f16* QKV = (f16*)(ws + WT_BYTES);
  f16* VT  = (f16*)(ws + WT_BYTES + QKV_BYTES);
  f16* X16 = (f16*)(ws + WT_BYTES + QKV_BYTES + VT_BYTES);

  prep<<<768 + 4096, 256, 0, stream>>>(Wq, Wk, Wv, x, WT, X16);
  gemm_qkv<<<1536, 256, 0, stream>>>(X16, WT, bq, bk, bv, QKV, VT);
  // attn: blockIdx.x = batch so linear id % 8 == batch -> XCD-local K/V in L2
  attn<<<dim3(BATCH, S_LEN / 32), 256, 0, stream>>>(
      QKV, QKV + (size_t)BATCH * S_LEN * UDIM, VT, out);
}